// Round 6
// baseline (739.644 us; speedup 1.0000x reference)
//
#include <hip/hip_runtime.h>
#include <cstddef>

// Problem constants (match reference)
#define N_NODES 100000
#define N_EDGES 1600000
#define E_TOT   (N_EDGES + N_NODES)   // edges + self loops = 1,700,000
#define IN_DIM  64
#define HIDDEN  128
#define Z_DIM   64

// ---------------- CSR build ----------------

__global__ __launch_bounds__(256) void init_cnt_k(int* cnt, int n) {
    int i = blockIdx.x * 256 + threadIdx.x;
    if (i < n) cnt[i] = 1;   // self loop
}

__global__ __launch_bounds__(256) void count_k(const int* __restrict__ dst, int* cnt, int e) {
    int i = blockIdx.x * 256 + threadIdx.x;
    if (i < e) atomicAdd(&cnt[dst[i]], 1);
}

__global__ __launch_bounds__(256) void dinv_k(const int* __restrict__ cnt, float* __restrict__ dinv, int n) {
    int i = blockIdx.x * 256 + threadIdx.x;
    if (i < n) dinv[i] = rsqrtf((float)cnt[i]);   // cnt >= 1 always
}

__global__ __launch_bounds__(256) void scan_block_k(const int* __restrict__ cnt, int* __restrict__ rowptr,
                                                    int* __restrict__ bsum, int n) {
    __shared__ int s[256];
    int tid = threadIdx.x;
    int i = blockIdx.x * 256 + tid;
    int v = (i < n) ? cnt[i] : 0;
    s[tid] = v;
    __syncthreads();
#pragma unroll
    for (int off = 1; off < 256; off <<= 1) {
        int t = (tid >= off) ? s[tid - off] : 0;
        __syncthreads();
        s[tid] += t;
        __syncthreads();
    }
    if (i < n) rowptr[i] = s[tid] - v;        // exclusive within block
    if (tid == 255) bsum[blockIdx.x] = s[255];
}

__global__ __launch_bounds__(512) void scan_bsum_k(int* bsum, int nb) {
    __shared__ int s[512];
    int tid = threadIdx.x;
    int v = (tid < nb) ? bsum[tid] : 0;
    s[tid] = v;
    __syncthreads();
#pragma unroll
    for (int off = 1; off < 512; off <<= 1) {
        int t = (tid >= off) ? s[tid - off] : 0;
        __syncthreads();
        s[tid] += t;
        __syncthreads();
    }
    if (tid < nb) bsum[tid] = s[tid] - v;     // exclusive
}

__global__ __launch_bounds__(256) void scan_add_k(int* __restrict__ rowptr, const int* __restrict__ bsum,
                                                  int* __restrict__ cursor, int n, int etot) {
    int i = blockIdx.x * 256 + threadIdx.x;
    if (i < n) {
        int val = rowptr[i] + bsum[blockIdx.x];
        rowptr[i] = val;
        cursor[i] = val;
    }
    if (i == 0) rowptr[n] = etot;
}

__global__ __launch_bounds__(256) void fill_k(const int* __restrict__ src, const int* __restrict__ dst,
                                              const float* __restrict__ dinv, int* cursor,
                                              int* __restrict__ col, float* __restrict__ nrm,
                                              int e, int n) {
    int i = blockIdx.x * 256 + threadIdx.x;
    if (i < e) {
        int s = src[i], d = dst[i];
        int p = atomicAdd(&cursor[d], 1);
        col[p] = s;
        nrm[p] = dinv[s] * dinv[d];
    } else if (i < e + n) {
        int v = i - e;
        int p = atomicAdd(&cursor[v], 1);
        col[p] = v;
        float dv = dinv[v];
        nrm[p] = dv * dv;
    }
}

// ---------------- Aggregation (gather): one wave per node (at LLC-fabric ceiling ~3.8 TB/s) --

template <int DIM>
__global__ __launch_bounds__(256) void agg_k(const float* __restrict__ H, const int* __restrict__ rowptr,
                                             const int* __restrict__ col, const float* __restrict__ nrm,
                                             float* __restrict__ out, int n) {
    int node = (int)((blockIdx.x * 256 + threadIdx.x) >> 6);
    if (node >= n) return;
    int lane = threadIdx.x & 63;
    int beg = rowptr[node], end = rowptr[node + 1];
    const float4* H4 = (const float4*)H;

    float4 acc; acc.x = 0.f; acc.y = 0.f; acc.z = 0.f; acc.w = 0.f;

    if constexpr (DIM == 128) {
        constexpr int RV = 32;
        int sub = lane >> 5;             // 0..1: which edge of a pair
        int fl  = lane & 31;
        for (int j = beg; j < end; j += 16) {
            int   s[8]; float w[8];
#pragma unroll
            for (int p = 0; p < 8; p++) {
                int idx = j + 2 * p + sub;
                int ci  = idx < end ? idx : beg;
                s[p] = col[ci];
                w[p] = idx < end ? nrm[ci] : 0.f;
            }
#pragma unroll
            for (int p = 0; p < 8; p++) {
                float4 v = H4[(size_t)s[p] * RV + fl];
                acc.x += w[p] * v.x; acc.y += w[p] * v.y;
                acc.z += w[p] * v.z; acc.w += w[p] * v.w;
            }
        }
        acc.x += __shfl_xor(acc.x, 32);
        acc.y += __shfl_xor(acc.y, 32);
        acc.z += __shfl_xor(acc.z, 32);
        acc.w += __shfl_xor(acc.w, 32);
        if (sub == 0) ((float4*)out)[(size_t)node * RV + fl] = acc;
    } else {
        constexpr int RV = 16;
        int sub = lane >> 4;             // 0..3: which edge of a quad
        int fl  = lane & 15;
        for (int j = beg; j < end; j += 32) {
            int   s[8]; float w[8];
#pragma unroll
            for (int p = 0; p < 8; p++) {
                int idx = j + 4 * p + sub;
                int ci  = idx < end ? idx : beg;
                s[p] = col[ci];
                w[p] = idx < end ? nrm[ci] : 0.f;
            }
#pragma unroll
            for (int p = 0; p < 8; p++) {
                float4 v = H4[(size_t)s[p] * RV + fl];
                acc.x += w[p] * v.x; acc.y += w[p] * v.y;
                acc.z += w[p] * v.z; acc.w += w[p] * v.w;
            }
        }
        acc.x += __shfl_xor(acc.x, 32);
        acc.y += __shfl_xor(acc.y, 32);
        acc.z += __shfl_xor(acc.z, 32);
        acc.w += __shfl_xor(acc.w, 32);
        acc.x += __shfl_xor(acc.x, 16);
        acc.y += __shfl_xor(acc.y, 16);
        acc.z += __shfl_xor(acc.z, 16);
        acc.w += __shfl_xor(acc.w, 16);
        if (sub == 0) ((float4*)out)[(size_t)node * RV + fl] = acc;
    }
}

// ---------------- Dense layer: 8 rows x 8 feats per thread, FMA-bound by design ----------
// Block = 256 threads, 128 nodes. fg=t&15 owns cols fg*4 (j=0) and fg*4+64 (j=1);
// mg=t>>4 owns rows mg*8+r (r=0..7). Per k per wave: W LDS = 2 ds_read_b128 (~24 cyc,
// 16 distinct addrs, 2-way bank alias = free) vs 16 FMA insts (32 cyc) -> FMA-bound.
// W staged in 32 KB chunks (KC=64): <=2 barriers total, 3 blocks/CU (grid-limited).
// A streamed from global, software-pipelined (prefetch next k4 into avn while computing).
// DUAL: j=0 cols -> Ca (mu), j=1 cols -> Cb (logvar); fused head GEMM.

template <int K, bool RELU, bool DUAL>
__global__ __launch_bounds__(256, 2) void gemm128_k(const float* __restrict__ A,
                                                    const float* __restrict__ Wa, const float* __restrict__ Wb,
                                                    const float* __restrict__ ba, const float* __restrict__ bb,
                                                    float* __restrict__ Ca, float* __restrict__ Cb, int n) {
    constexpr int F  = 128;
    constexpr int NT = 128;          // nodes per block
    constexpr int KC = 64;           // W chunk rows (32 KB)
    __shared__ __align__(16) float Ws[KC * F];

    int t  = threadIdx.x;
    int fg = t & 15;
    int mg = t >> 4;
    int m0 = blockIdx.x * NT;

    // clamped row pointers (tail block: duplicate last row, stores guarded)
    const float* Ap[8];
#pragma unroll
    for (int r = 0; r < 8; r++) {
        int row = m0 + mg * 8 + r;
        Ap[r] = A + (size_t)(row < n ? row : (n - 1)) * K;
    }

    float4 acc[8][2];
#pragma unroll
    for (int r = 0; r < 8; r++)
#pragma unroll
        for (int j = 0; j < 2; j++) { acc[r][j].x = 0.f; acc[r][j].y = 0.f; acc[r][j].z = 0.f; acc[r][j].w = 0.f; }

    // prime A pipeline
    float4 av[8];
#pragma unroll
    for (int r = 0; r < 8; r++) av[r] = *(const float4*)&Ap[r][0];

    for (int c = 0; c < K; c += KC) {
        if (c) __syncthreads();      // chunk0 reads done before restage
        // stage W chunk: KC*F/4 = 2048 float4, coalesced, 8 per thread
        for (int e = t; e < KC * F / 4; e += 256) {
            float4 w;
            if (!DUAL) {
                w = ((const float4*)Wa)[(size_t)c * (F / 4) + e];
            } else {
                int r  = e >> 5;             // k row within chunk
                int cc = (e & 31) * 4;       // float col 0..127
                w = (cc < 64) ? *(const float4*)&Wa[(size_t)(c + r) * 64 + cc]
                              : *(const float4*)&Wb[(size_t)(c + r) * 64 + (cc - 64)];
            }
            ((float4*)Ws)[e] = w;
        }
        __syncthreads();

        for (int k4 = 0; k4 < KC; k4 += 4) {
            int gk = c + k4;
            float4 avn[8];
            bool more = (gk + 4) < K;
            if (more) {
#pragma unroll
                for (int r = 0; r < 8; r++) avn[r] = *(const float4*)&Ap[r][gk + 4];
            }
#pragma unroll
            for (int kk = 0; kk < 4; kk++) {
                float4 w0 = ((const float4*)Ws)[(k4 + kk) * (F / 4) + fg];
                float4 w1 = ((const float4*)Ws)[(k4 + kk) * (F / 4) + fg + 16];
#pragma unroll
                for (int r = 0; r < 8; r++) {
                    float a = ((const float*)&av[r])[kk];
                    acc[r][0].x += a * w0.x; acc[r][0].y += a * w0.y;
                    acc[r][0].z += a * w0.z; acc[r][0].w += a * w0.w;
                    acc[r][1].x += a * w1.x; acc[r][1].y += a * w1.y;
                    acc[r][1].z += a * w1.z; acc[r][1].w += a * w1.w;
                }
            }
            if (more) {
#pragma unroll
                for (int r = 0; r < 8; r++) av[r] = avn[r];
            }
        }
    }

    // epilogue: bias + optional relu; DUAL: j=0 -> Ca (cols 0..63), j=1 -> Cb
#pragma unroll
    for (int r = 0; r < 8; r++) {
        int node = m0 + mg * 8 + r;
        if (node >= n) break;
#pragma unroll
        for (int j = 0; j < 2; j++) {
            float4 v = acc[r][j];
            const float* bp;
            float* cp;
            int fo;
            if (!DUAL) {
                bp = ba; cp = Ca + (size_t)node * F; fo = fg * 4 + 64 * j;
            } else if (j == 0) {
                bp = ba; cp = Ca + (size_t)node * 64; fo = fg * 4;
            } else {
                bp = bb; cp = Cb + (size_t)node * 64; fo = fg * 4;
            }
            v.x += bp[fo + 0]; v.y += bp[fo + 1]; v.z += bp[fo + 2]; v.w += bp[fo + 3];
            if (RELU) {
                v.x = fmaxf(v.x, 0.f); v.y = fmaxf(v.y, 0.f);
                v.z = fmaxf(v.z, 0.f); v.w = fmaxf(v.w, 0.f);
            }
            *(float4*)&cp[fo] = v;
        }
    }
}

// ---------------- launch ----------------

extern "C" void kernel_launch(void* const* d_in, const int* in_sizes, int n_in,
                              void* d_out, int out_size, void* d_ws, size_t ws_size,
                              hipStream_t stream) {
    const int N = N_NODES, E = N_EDGES, ETOT = E_TOT;

    const float* x    = (const float*)d_in[0];
    const int*   ei   = (const int*)d_in[1];
    const int*   srcA = ei;
    const int*   dstA = ei + E;
    const float* W1   = (const float*)d_in[2];
    const float* b1   = (const float*)d_in[3];
    const float* W2   = (const float*)d_in[4];
    const float* b2   = (const float*)d_in[5];
    const float* Wmu  = (const float*)d_in[6];
    const float* bmu  = (const float*)d_in[7];
    const float* Wlv  = (const float*)d_in[8];
    const float* blv  = (const float*)d_in[9];
    float* out = (float*)d_out;

    // workspace carve-out (~117 MB)
    char* ws = (char*)d_ws;
    size_t o = 0;
    auto alloc = [&](size_t bytes) -> void* {
        o = (o + 255) & ~(size_t)255;
        void* p = ws + o;
        o += bytes;
        return p;
    };
    int*   cnt    = (int*)alloc((size_t)N * 4);          // deg counts, later cursor
    int*   rowptr = (int*)alloc((size_t)(N + 1) * 4);
    float* dinv   = (float*)alloc((size_t)N * 4);
    int*   bsum   = (int*)alloc(512 * 4);
    int*   col    = (int*)alloc((size_t)ETOT * 4);
    float* nrm    = (float*)alloc((size_t)ETOT * 4);
    float* agg    = (float*)alloc((size_t)N * HIDDEN * 4);
    float* h      = (float*)alloc((size_t)N * HIDDEN * 4);
    (void)ws_size;

    const int gN = (N + 255) / 256;          // 391
    const int gE = (E + 255) / 256;          // 6250
    const int gT = (ETOT + 255) / 256;       // 6641
    const int gAgg = (N + 3) / 4;            // 25000 (4 nodes/block)
    const int gGemm = (N + 127) / 128;       // 782

    // CSR build
    init_cnt_k<<<gN, 256, 0, stream>>>(cnt, N);
    count_k<<<gE, 256, 0, stream>>>(dstA, cnt, E);
    dinv_k<<<gN, 256, 0, stream>>>(cnt, dinv, N);
    scan_block_k<<<gN, 256, 0, stream>>>(cnt, rowptr, bsum, N);
    scan_bsum_k<<<1, 512, 0, stream>>>(bsum, gN);
    scan_add_k<<<gN, 256, 0, stream>>>(rowptr, bsum, cnt /*cursor*/, N, ETOT);
    fill_k<<<gT, 256, 0, stream>>>(srcA, dstA, dinv, cnt, col, nrm, E, N);

    // layer 1: h = relu(Agg(x) @ W1 + b1)      (aggregate in 64-dim!)
    agg_k<64><<<gAgg, 256, 0, stream>>>(x, rowptr, col, nrm, agg, N);
    gemm128_k<64, true, false><<<gGemm, 256, 0, stream>>>(agg, W1, nullptr, b1, nullptr, h, nullptr, N);

    // layer 2: h = relu(Agg(h) @ W2 + b2)
    agg_k<128><<<gAgg, 256, 0, stream>>>(h, rowptr, col, nrm, agg, N);
    gemm128_k<128, true, false><<<gGemm, 256, 0, stream>>>(agg, W2, nullptr, b2, nullptr, h, nullptr, N);

    // heads: aggregate once, ONE fused GEMM (j=0 cols = mu, j=1 cols = logvar)
    agg_k<128><<<gAgg, 256, 0, stream>>>(h, rowptr, col, nrm, agg, N);
    gemm128_k<128, false, true><<<gGemm, 256, 0, stream>>>(agg, Wmu, Wlv, bmu, blv,
                                                           out, out + (size_t)N * Z_DIM, N);
}

// Round 7
// 690.260 us; speedup vs baseline: 1.0715x; 1.0715x over previous
//
#include <hip/hip_runtime.h>
#include <cstddef>

// Problem constants (match reference)
#define N_NODES 100000
#define N_EDGES 1600000
#define E_TOT   (N_EDGES + N_NODES)   // edges + self loops = 1,700,000
#define IN_DIM  64
#define HIDDEN  128
#define Z_DIM   64

// ---------------- CSR build ----------------

__global__ __launch_bounds__(256) void init_cnt_k(int* cnt, int n) {
    int i = blockIdx.x * 256 + threadIdx.x;
    if (i < n) cnt[i] = 1;   // self loop
}

__global__ __launch_bounds__(256) void count_k(const int* __restrict__ dst, int* cnt, int e) {
    int i = blockIdx.x * 256 + threadIdx.x;
    if (i < e) atomicAdd(&cnt[dst[i]], 1);
}

// block-level exclusive scan of cnt -> rowptr (+ per-block sums); also emits dinv = rsqrt(deg)
__global__ __launch_bounds__(256) void scan_block_k(const int* __restrict__ cnt, int* __restrict__ rowptr,
                                                    int* __restrict__ bsum, float* __restrict__ dinv, int n) {
    __shared__ int s[256];
    int tid = threadIdx.x;
    int i = blockIdx.x * 256 + tid;
    int v = (i < n) ? cnt[i] : 0;
    if (i < n) dinv[i] = rsqrtf((float)v);    // v >= 1 always (self loop)
    s[tid] = v;
    __syncthreads();
#pragma unroll
    for (int off = 1; off < 256; off <<= 1) {
        int t = (tid >= off) ? s[tid - off] : 0;
        __syncthreads();
        s[tid] += t;
        __syncthreads();
    }
    if (i < n) rowptr[i] = s[tid] - v;        // exclusive within block
    if (tid == 255) bsum[blockIdx.x] = s[255];
}

__global__ __launch_bounds__(512) void scan_bsum_k(int* bsum, int nb) {
    __shared__ int s[512];
    int tid = threadIdx.x;
    int v = (tid < nb) ? bsum[tid] : 0;
    s[tid] = v;
    __syncthreads();
#pragma unroll
    for (int off = 1; off < 512; off <<= 1) {
        int t = (tid >= off) ? s[tid - off] : 0;
        __syncthreads();
        s[tid] += t;
        __syncthreads();
    }
    if (tid < nb) bsum[tid] = s[tid] - v;     // exclusive
}

__global__ __launch_bounds__(256) void scan_add_k(int* __restrict__ rowptr, const int* __restrict__ bsum,
                                                  int* __restrict__ cursor, int n, int etot) {
    int i = blockIdx.x * 256 + threadIdx.x;
    if (i < n) {
        int val = rowptr[i] + bsum[blockIdx.x];
        rowptr[i] = val;
        cursor[i] = val;
    }
    if (i == 0) rowptr[n] = etot;
}

// fill packed edge meta: em[p] = {src, bits(norm)} -- ONE 8B scattered store per edge
// (was two 4B stores to two arrays = two random cachelines; R6 post-mortem).
__global__ __launch_bounds__(256) void fill_k(const int* __restrict__ src, const int* __restrict__ dst,
                                              const float* __restrict__ dinv, int* cursor,
                                              int2* __restrict__ em, int e, int n) {
    int i = blockIdx.x * 256 + threadIdx.x;
    if (i < e) {
        int s = src[i], d = dst[i];
        int p = atomicAdd(&cursor[d], 1);
        em[p] = make_int2(s, __float_as_int(dinv[s] * dinv[d]));
    } else if (i < e + n) {
        int v = i - e;
        int p = atomicAdd(&cursor[v], 1);
        float dv = dinv[v];
        em[p] = make_int2(v, __float_as_int(dv * dv));
    }
}

// ---------------- Aggregation (gather): one wave per node (at LLC-fabric ceiling ~3.8 TB/s) --
// Edge meta is packed int2 {col, nrm}. DIM=128: 16 edges/iter, 2 half-waves; DIM=64: 32/iter,
// 4 quarter-waves. OOB edges clamp-indexed with weight 0 (beg<end always: self-loop).

template <int DIM>
__global__ __launch_bounds__(256) void agg_k(const float* __restrict__ H, const int* __restrict__ rowptr,
                                             const int2* __restrict__ em, float* __restrict__ out, int n) {
    int node = (int)((blockIdx.x * 256 + threadIdx.x) >> 6);
    if (node >= n) return;
    int lane = threadIdx.x & 63;
    int beg = rowptr[node], end = rowptr[node + 1];
    const float4* H4 = (const float4*)H;

    float4 acc; acc.x = 0.f; acc.y = 0.f; acc.z = 0.f; acc.w = 0.f;

    if constexpr (DIM == 128) {
        constexpr int RV = 32;
        int sub = lane >> 5;             // 0..1: which edge of a pair
        int fl  = lane & 31;
        for (int j = beg; j < end; j += 16) {
            int   s[8]; float w[8];
#pragma unroll
            for (int p = 0; p < 8; p++) {
                int idx = j + 2 * p + sub;
                int ci  = idx < end ? idx : beg;
                int2 e  = em[ci];
                s[p] = e.x;
                w[p] = idx < end ? __int_as_float(e.y) : 0.f;
            }
#pragma unroll
            for (int p = 0; p < 8; p++) {
                float4 v = H4[(size_t)s[p] * RV + fl];
                acc.x += w[p] * v.x; acc.y += w[p] * v.y;
                acc.z += w[p] * v.z; acc.w += w[p] * v.w;
            }
        }
        acc.x += __shfl_xor(acc.x, 32);
        acc.y += __shfl_xor(acc.y, 32);
        acc.z += __shfl_xor(acc.z, 32);
        acc.w += __shfl_xor(acc.w, 32);
        if (sub == 0) ((float4*)out)[(size_t)node * RV + fl] = acc;
    } else {
        constexpr int RV = 16;
        int sub = lane >> 4;             // 0..3: which edge of a quad
        int fl  = lane & 15;
        for (int j = beg; j < end; j += 32) {
            int   s[8]; float w[8];
#pragma unroll
            for (int p = 0; p < 8; p++) {
                int idx = j + 4 * p + sub;
                int ci  = idx < end ? idx : beg;
                int2 e  = em[ci];
                s[p] = e.x;
                w[p] = idx < end ? __int_as_float(e.y) : 0.f;
            }
#pragma unroll
            for (int p = 0; p < 8; p++) {
                float4 v = H4[(size_t)s[p] * RV + fl];
                acc.x += w[p] * v.x; acc.y += w[p] * v.y;
                acc.z += w[p] * v.z; acc.w += w[p] * v.w;
            }
        }
        acc.x += __shfl_xor(acc.x, 32);
        acc.y += __shfl_xor(acc.y, 32);
        acc.z += __shfl_xor(acc.z, 32);
        acc.w += __shfl_xor(acc.w, 32);
        acc.x += __shfl_xor(acc.x, 16);
        acc.y += __shfl_xor(acc.y, 16);
        acc.z += __shfl_xor(acc.z, 16);
        acc.w += __shfl_xor(acc.w, 16);
        if (sub == 0) ((float4*)out)[(size_t)node * RV + fl] = acc;
    }
}

// ---------------- Dense layer: whole W in LDS, ONE barrier, A streamed from global --------
// (R5 variant, measured best.) Block = 256 threads, 128 nodes. fg=t&7 owns feats fg*4+32*j
// (float4 idx fg+8j -> banks 4fg..4fg+3, 8-lane broadcast: conflict-free). mg=t>>3 owns rows
// mg*4+r; A row read by 8 threads of same wave -> 8 rows * 16B = 128B per load instr.
// DUAL: output cols 0..63 = Wa/ba -> Ca, 64..127 = Wb/bb -> Cb (fused mu/logvar heads).

template <int K, bool RELU, bool DUAL>
__global__ __launch_bounds__(256, 3) void gemm128_k(const float* __restrict__ A,
                                                    const float* __restrict__ Wa, const float* __restrict__ Wb,
                                                    const float* __restrict__ ba, const float* __restrict__ bb,
                                                    float* __restrict__ Ca, float* __restrict__ Cb, int n) {
    constexpr int F  = 128;
    constexpr int NT = 128;          // nodes per block
    __shared__ __align__(16) float Ws[K * F];    // 32 KB (K=64) / 64 KB (K=128)

    int t  = threadIdx.x;
    int fg = t & 7;
    int mg = t >> 3;
    int m0 = blockIdx.x * NT;

    // stage whole W (K*F/4 float4, coalesced)
    for (int e = t; e < K * F / 4; e += 256) {
        float4 w;
        if (!DUAL) {
            w = ((const float4*)Wa)[e];
        } else {
            int r = e >> 5;              // k row
            int c = (e & 31) * 4;        // float col 0..127
            w = (c < 64) ? *(const float4*)&Wa[(size_t)r * 64 + c]
                         : *(const float4*)&Wb[(size_t)r * 64 + (c - 64)];
        }
        ((float4*)Ws)[e] = w;
    }
    __syncthreads();

    // row pointers (clamped; garbage rows computed but not stored)
    const float* Ap[4];
#pragma unroll
    for (int r = 0; r < 4; r++) {
        int row = m0 + mg * 4 + r;
        Ap[r] = A + (size_t)(row < n ? row : (n - 1)) * K;
    }

    float4 acc[4][4];                // [r][j]
#pragma unroll
    for (int r = 0; r < 4; r++)
#pragma unroll
        for (int j = 0; j < 4; j++) { acc[r][j].x = 0.f; acc[r][j].y = 0.f; acc[r][j].z = 0.f; acc[r][j].w = 0.f; }

    for (int k4 = 0; k4 < K; k4 += 4) {
        float4 av[4];
#pragma unroll
        for (int r = 0; r < 4; r++) av[r] = *(const float4*)&Ap[r][k4];
#pragma unroll
        for (int kk = 0; kk < 4; kk++) {
            float a0 = ((const float*)&av[0])[kk];
            float a1 = ((const float*)&av[1])[kk];
            float a2 = ((const float*)&av[2])[kk];
            float a3 = ((const float*)&av[3])[kk];
#pragma unroll
            for (int j = 0; j < 4; j++) {
                float4 w = ((const float4*)Ws)[(k4 + kk) * (F / 4) + fg + 8 * j];
                acc[0][j].x += a0 * w.x; acc[0][j].y += a0 * w.y; acc[0][j].z += a0 * w.z; acc[0][j].w += a0 * w.w;
                acc[1][j].x += a1 * w.x; acc[1][j].y += a1 * w.y; acc[1][j].z += a1 * w.z; acc[1][j].w += a1 * w.w;
                acc[2][j].x += a2 * w.x; acc[2][j].y += a2 * w.y; acc[2][j].z += a2 * w.z; acc[2][j].w += a2 * w.w;
                acc[3][j].x += a3 * w.x; acc[3][j].y += a3 * w.y; acc[3][j].z += a3 * w.z; acc[3][j].w += a3 * w.w;
            }
        }
    }

    // epilogue: bias + optional relu; DUAL splits cols 0..63 / 64..127
#pragma unroll
    for (int r = 0; r < 4; r++) {
        int node = m0 + mg * 4 + r;
        if (node >= n) break;
#pragma unroll
        for (int j = 0; j < 4; j++) {
            int f = fg * 4 + 32 * j;
            float4 v = acc[r][j];
            const float* bp;
            float* cp;
            int fo;
            if (!DUAL) {
                bp = ba; cp = Ca + (size_t)node * F; fo = f;
            } else if (j < 2) {              // f < 64
                bp = ba; cp = Ca + (size_t)node * 64; fo = f;
            } else {
                bp = bb; cp = Cb + (size_t)node * 64; fo = f - 64;
            }
            v.x += bp[fo + 0]; v.y += bp[fo + 1]; v.z += bp[fo + 2]; v.w += bp[fo + 3];
            if (RELU) {
                v.x = fmaxf(v.x, 0.f); v.y = fmaxf(v.y, 0.f);
                v.z = fmaxf(v.z, 0.f); v.w = fmaxf(v.w, 0.f);
            }
            *(float4*)&cp[fo] = v;
        }
    }
}

// ---------------- launch ----------------

extern "C" void kernel_launch(void* const* d_in, const int* in_sizes, int n_in,
                              void* d_out, int out_size, void* d_ws, size_t ws_size,
                              hipStream_t stream) {
    const int N = N_NODES, E = N_EDGES, ETOT = E_TOT;

    const float* x    = (const float*)d_in[0];
    const int*   ei   = (const int*)d_in[1];
    const int*   srcA = ei;
    const int*   dstA = ei + E;
    const float* W1   = (const float*)d_in[2];
    const float* b1   = (const float*)d_in[3];
    const float* W2   = (const float*)d_in[4];
    const float* b2   = (const float*)d_in[5];
    const float* Wmu  = (const float*)d_in[6];
    const float* bmu  = (const float*)d_in[7];
    const float* Wlv  = (const float*)d_in[8];
    const float* blv  = (const float*)d_in[9];
    float* out = (float*)d_out;

    // workspace carve-out
    char* ws = (char*)d_ws;
    size_t o = 0;
    auto alloc = [&](size_t bytes) -> void* {
        o = (o + 255) & ~(size_t)255;
        void* p = ws + o;
        o += bytes;
        return p;
    };
    int*   cnt    = (int*)alloc((size_t)N * 4);          // deg counts, later cursor
    int*   rowptr = (int*)alloc((size_t)(N + 1) * 4);
    float* dinv   = (float*)alloc((size_t)N * 4);
    int*   bsum   = (int*)alloc(512 * 4);
    int2*  em     = (int2*)alloc((size_t)ETOT * 8);      // packed {col, nrm}
    float* agg    = (float*)alloc((size_t)N * HIDDEN * 4);
    float* h      = (float*)alloc((size_t)N * HIDDEN * 4);
    (void)ws_size;

    const int gN = (N + 255) / 256;          // 391
    const int gE = (E + 255) / 256;          // 6250
    const int gT = (ETOT + 255) / 256;       // 6641
    const int gAgg = (N + 3) / 4;            // 25000 (4 nodes/block)
    const int gGemm = (N + 127) / 128;       // 782

    // CSR build
    init_cnt_k<<<gN, 256, 0, stream>>>(cnt, N);
    count_k<<<gE, 256, 0, stream>>>(dstA, cnt, E);
    scan_block_k<<<gN, 256, 0, stream>>>(cnt, rowptr, bsum, dinv, N);
    scan_bsum_k<<<1, 512, 0, stream>>>(bsum, gN);
    scan_add_k<<<gN, 256, 0, stream>>>(rowptr, bsum, cnt /*cursor*/, N, ETOT);
    fill_k<<<gT, 256, 0, stream>>>(srcA, dstA, dinv, cnt, em, E, N);

    // layer 1: h = relu(Agg(x) @ W1 + b1)      (aggregate in 64-dim!)
    agg_k<64><<<gAgg, 256, 0, stream>>>(x, rowptr, em, agg, N);
    gemm128_k<64, true, false><<<gGemm, 256, 0, stream>>>(agg, W1, nullptr, b1, nullptr, h, nullptr, N);

    // layer 2: h = relu(Agg(h) @ W2 + b2)
    agg_k<128><<<gAgg, 256, 0, stream>>>(h, rowptr, em, agg, N);
    gemm128_k<128, true, false><<<gGemm, 256, 0, stream>>>(agg, W2, nullptr, b2, nullptr, h, nullptr, N);

    // heads: aggregate once, ONE fused GEMM (cols 0..63 = mu, 64..127 = logvar)
    agg_k<128><<<gAgg, 256, 0, stream>>>(h, rowptr, em, agg, N);
    gemm128_k<128, false, true><<<gGemm, 256, 0, stream>>>(agg, Wmu, Wlv, bmu, blv,
                                                           out, out + (size_t)N * Z_DIM, N);
}

// Round 8
// 546.203 us; speedup vs baseline: 1.3542x; 1.2637x over previous
//
#include <hip/hip_runtime.h>
#include <hip/hip_fp16.h>
#include <cstddef>

// Problem constants (match reference)
#define N_NODES 100000
#define N_EDGES 1600000
#define E_TOT   (N_EDGES + N_NODES)   // edges + self loops = 1,700,000
#define IN_DIM  64
#define HIDDEN  128
#define Z_DIM   64

// ---------------- CSR build ----------------

__global__ __launch_bounds__(256) void init_cnt_k(int* cnt, int n) {
    int i = blockIdx.x * 256 + threadIdx.x;
    if (i < n) cnt[i] = 1;   // self loop
}

__global__ __launch_bounds__(256) void count_k(const int* __restrict__ dst, int* cnt, int e) {
    int i = blockIdx.x * 256 + threadIdx.x;
    if (i < e) atomicAdd(&cnt[dst[i]], 1);
}

// block-level exclusive scan of cnt -> rowptr (+ per-block sums); also emits dinv = rsqrt(deg)
__global__ __launch_bounds__(256) void scan_block_k(const int* __restrict__ cnt, int* __restrict__ rowptr,
                                                    int* __restrict__ bsum, float* __restrict__ dinv, int n) {
    __shared__ int s[256];
    int tid = threadIdx.x;
    int i = blockIdx.x * 256 + tid;
    int v = (i < n) ? cnt[i] : 0;
    if (i < n) dinv[i] = rsqrtf((float)v);    // v >= 1 always (self loop)
    s[tid] = v;
    __syncthreads();
#pragma unroll
    for (int off = 1; off < 256; off <<= 1) {
        int t = (tid >= off) ? s[tid - off] : 0;
        __syncthreads();
        s[tid] += t;
        __syncthreads();
    }
    if (i < n) rowptr[i] = s[tid] - v;        // exclusive within block
    if (tid == 255) bsum[blockIdx.x] = s[255];
}

__global__ __launch_bounds__(512) void scan_bsum_k(int* bsum, int nb) {
    __shared__ int s[512];
    int tid = threadIdx.x;
    int v = (tid < nb) ? bsum[tid] : 0;
    s[tid] = v;
    __syncthreads();
#pragma unroll
    for (int off = 1; off < 512; off <<= 1) {
        int t = (tid >= off) ? s[tid - off] : 0;
        __syncthreads();
        s[tid] += t;
        __syncthreads();
    }
    if (tid < nb) bsum[tid] = s[tid] - v;     // exclusive
}

__global__ __launch_bounds__(256) void scan_add_k(int* __restrict__ rowptr, const int* __restrict__ bsum,
                                                  int* __restrict__ cursor, int n, int etot) {
    int i = blockIdx.x * 256 + threadIdx.x;
    if (i < n) {
        int val = rowptr[i] + bsum[blockIdx.x];
        rowptr[i] = val;
        cursor[i] = val;
    }
    if (i == 0) rowptr[n] = etot;
}

// fill packed edge meta: em[p] = {src, bits(norm)} -- one 8B scattered store per edge
__global__ __launch_bounds__(256) void fill_k(const int* __restrict__ src, const int* __restrict__ dst,
                                              const float* __restrict__ dinv, int* cursor,
                                              int2* __restrict__ em, int e, int n) {
    int i = blockIdx.x * 256 + threadIdx.x;
    if (i < e) {
        int s = src[i], d = dst[i];
        int p = atomicAdd(&cursor[d], 1);
        em[p] = make_int2(s, __float_as_int(dinv[s] * dinv[d]));
    } else if (i < e + n) {
        int v = i - e;
        int p = atomicAdd(&cursor[v], 1);
        float dv = dinv[v];
        em[p] = make_int2(v, __float_as_int(dv * dv));
    }
}

// cast fp32 -> fp16, 8 elems per thread (total must be divisible by 8)
__global__ __launch_bounds__(256) void cast16_k(const float* __restrict__ in, __half* __restrict__ out, int total8) {
    int i = blockIdx.x * 256 + threadIdx.x;
    if (i >= total8) return;
    const float4* in4 = (const float4*)in;
    float4 a = in4[2 * i], b = in4[2 * i + 1];
    __half2 h0 = __floats2half2_rn(a.x, a.y);
    __half2 h1 = __floats2half2_rn(a.z, a.w);
    __half2 h2 = __floats2half2_rn(b.x, b.y);
    __half2 h3 = __floats2half2_rn(b.z, b.w);
    uint4 pk = make_uint4(*(unsigned*)&h0, *(unsigned*)&h1, *(unsigned*)&h2, *(unsigned*)&h3);
    ((uint4*)out)[i] = pk;
}

// ---------------- Aggregation (gather): fp16 rows, fp32 accumulate ----------------
// Row = DIM*2 bytes. Lane loads 16B (8 halves): DIM=128 -> 16 lanes/row (4 edges per load
// instr), DIM=64 -> 8 lanes/row (8 edges per instr). 4 loads in flight per iter (4 KB/wave,
// 16 or 32 edges). OOB edges clamp-indexed with weight 0 (beg<end always: self-loop).
// Output fp32 (coalesced), accumulation fp32.

template <int DIM>
__global__ __launch_bounds__(256) void agg_k(const __half* __restrict__ H, const int* __restrict__ rowptr,
                                             const int2* __restrict__ em, float* __restrict__ out, int n) {
    int node = (int)((blockIdx.x * 256 + threadIdx.x) >> 6);
    if (node >= n) return;
    int lane = threadIdx.x & 63;
    int beg = rowptr[node], end = rowptr[node + 1];
    const uint4* H4 = (const uint4*)H;       // 8 halves per uint4

    constexpr int RV   = DIM / 8;            // 16B-chunks per row (128->16, 64->8)
    constexpr int SUBS = 64 / RV;            // edges per load instr (4 or 8)
    int sub = lane / RV;
    int fl  = lane % RV;

    float acc[8];
#pragma unroll
    for (int q = 0; q < 8; q++) acc[q] = 0.f;

    for (int j = beg; j < end; j += SUBS * 4) {
        int   s[4]; float w[4];
#pragma unroll
        for (int p = 0; p < 4; p++) {
            int idx = j + SUBS * p + sub;
            int ci  = idx < end ? idx : beg;
            int2 e  = em[ci];
            s[p] = e.x;
            w[p] = idx < end ? __int_as_float(e.y) : 0.f;
        }
#pragma unroll
        for (int p = 0; p < 4; p++) {
            uint4 v = H4[(size_t)s[p] * RV + fl];
            const __half2* hp = (const __half2*)&v;
            float2 f0 = __half22float2(hp[0]);
            float2 f1 = __half22float2(hp[1]);
            float2 f2 = __half22float2(hp[2]);
            float2 f3 = __half22float2(hp[3]);
            acc[0] += w[p] * f0.x; acc[1] += w[p] * f0.y;
            acc[2] += w[p] * f1.x; acc[3] += w[p] * f1.y;
            acc[4] += w[p] * f2.x; acc[5] += w[p] * f2.y;
            acc[6] += w[p] * f3.x; acc[7] += w[p] * f3.y;
        }
    }
    // combine sub-waves: xor-reduce down to sub==0
#pragma unroll
    for (int off = 32; off >= RV; off >>= 1) {
#pragma unroll
        for (int q = 0; q < 8; q++) acc[q] += __shfl_xor(acc[q], off);
    }
    if (sub == 0) {
        float* op = out + (size_t)node * DIM + fl * 8;
        float4 v0 = make_float4(acc[0], acc[1], acc[2], acc[3]);
        float4 v1 = make_float4(acc[4], acc[5], acc[6], acc[7]);
        *(float4*)op = v0;
        *(float4*)(op + 4) = v1;
    }
}

// ---------------- Dense layer: whole W in LDS, ONE barrier, A streamed from global --------
// (R5 compute structure, measured best.) Block = 256 threads, 128 nodes. fg=t&7 owns feats
// fg*4+32*j; mg=t>>3 owns rows mg*4+r. OUTT=__half: hidden layers emit fp16 rows for the
// next gather; OUTT=float: head GEMM emits fp32. DUAL: cols 0..63 -> Ca (mu), 64..127 -> Cb.

template <int K, bool RELU, bool DUAL, typename OUTT>
__global__ __launch_bounds__(256, 3) void gemm128_k(const float* __restrict__ A,
                                                    const float* __restrict__ Wa, const float* __restrict__ Wb,
                                                    const float* __restrict__ ba, const float* __restrict__ bb,
                                                    OUTT* __restrict__ Ca, OUTT* __restrict__ Cb, int n) {
    constexpr int F  = 128;
    constexpr int NT = 128;          // nodes per block
    __shared__ __align__(16) float Ws[K * F];    // 32 KB (K=64) / 64 KB (K=128)

    int t  = threadIdx.x;
    int fg = t & 7;
    int mg = t >> 3;
    int m0 = blockIdx.x * NT;

    // stage whole W (K*F/4 float4, coalesced)
    for (int e = t; e < K * F / 4; e += 256) {
        float4 w;
        if (!DUAL) {
            w = ((const float4*)Wa)[e];
        } else {
            int r = e >> 5;              // k row
            int c = (e & 31) * 4;        // float col 0..127
            w = (c < 64) ? *(const float4*)&Wa[(size_t)r * 64 + c]
                         : *(const float4*)&Wb[(size_t)r * 64 + (c - 64)];
        }
        ((float4*)Ws)[e] = w;
    }
    __syncthreads();

    // row pointers (clamped; garbage rows computed but not stored)
    const float* Ap[4];
#pragma unroll
    for (int r = 0; r < 4; r++) {
        int row = m0 + mg * 4 + r;
        Ap[r] = A + (size_t)(row < n ? row : (n - 1)) * K;
    }

    float4 acc[4][4];                // [r][j]
#pragma unroll
    for (int r = 0; r < 4; r++)
#pragma unroll
        for (int j = 0; j < 4; j++) { acc[r][j].x = 0.f; acc[r][j].y = 0.f; acc[r][j].z = 0.f; acc[r][j].w = 0.f; }

    for (int k4 = 0; k4 < K; k4 += 4) {
        float4 av[4];
#pragma unroll
        for (int r = 0; r < 4; r++) av[r] = *(const float4*)&Ap[r][k4];
#pragma unroll
        for (int kk = 0; kk < 4; kk++) {
            float a0 = ((const float*)&av[0])[kk];
            float a1 = ((const float*)&av[1])[kk];
            float a2 = ((const float*)&av[2])[kk];
            float a3 = ((const float*)&av[3])[kk];
#pragma unroll
            for (int j = 0; j < 4; j++) {
                float4 w = ((const float4*)Ws)[(k4 + kk) * (F / 4) + fg + 8 * j];
                acc[0][j].x += a0 * w.x; acc[0][j].y += a0 * w.y; acc[0][j].z += a0 * w.z; acc[0][j].w += a0 * w.w;
                acc[1][j].x += a1 * w.x; acc[1][j].y += a1 * w.y; acc[1][j].z += a1 * w.z; acc[1][j].w += a1 * w.w;
                acc[2][j].x += a2 * w.x; acc[2][j].y += a2 * w.y; acc[2][j].z += a2 * w.z; acc[2][j].w += a2 * w.w;
                acc[3][j].x += a3 * w.x; acc[3][j].y += a3 * w.y; acc[3][j].z += a3 * w.z; acc[3][j].w += a3 * w.w;
            }
        }
    }

    // epilogue: bias + optional relu; DUAL splits cols 0..63 / 64..127
#pragma unroll
    for (int r = 0; r < 4; r++) {
        int node = m0 + mg * 4 + r;
        if (node >= n) break;
#pragma unroll
        for (int j = 0; j < 4; j++) {
            int f = fg * 4 + 32 * j;
            float4 v = acc[r][j];
            const float* bp;
            OUTT* cp;
            int fo;
            if (!DUAL) {
                bp = ba; cp = Ca + (size_t)node * F; fo = f;
            } else if (j < 2) {              // f < 64
                bp = ba; cp = Ca + (size_t)node * 64; fo = f;
            } else {
                bp = bb; cp = Cb + (size_t)node * 64; fo = f - 64;
            }
            v.x += bp[fo + 0]; v.y += bp[fo + 1]; v.z += bp[fo + 2]; v.w += bp[fo + 3];
            if (RELU) {
                v.x = fmaxf(v.x, 0.f); v.y = fmaxf(v.y, 0.f);
                v.z = fmaxf(v.z, 0.f); v.w = fmaxf(v.w, 0.f);
            }
            if constexpr (sizeof(OUTT) == 2) {
                __half2 p01 = __floats2half2_rn(v.x, v.y);
                __half2 p23 = __floats2half2_rn(v.z, v.w);
                uint2 pk = make_uint2(*(unsigned*)&p01, *(unsigned*)&p23);
                *(uint2*)&cp[fo] = pk;       // 8B fp16 store
            } else {
                *(float4*)&cp[fo] = v;
            }
        }
    }
}

// ---------------- launch ----------------

extern "C" void kernel_launch(void* const* d_in, const int* in_sizes, int n_in,
                              void* d_out, int out_size, void* d_ws, size_t ws_size,
                              hipStream_t stream) {
    const int N = N_NODES, E = N_EDGES, ETOT = E_TOT;

    const float* x    = (const float*)d_in[0];
    const int*   ei   = (const int*)d_in[1];
    const int*   srcA = ei;
    const int*   dstA = ei + E;
    const float* W1   = (const float*)d_in[2];
    const float* b1   = (const float*)d_in[3];
    const float* W2   = (const float*)d_in[4];
    const float* b2   = (const float*)d_in[5];
    const float* Wmu  = (const float*)d_in[6];
    const float* bmu  = (const float*)d_in[7];
    const float* Wlv  = (const float*)d_in[8];
    const float* blv  = (const float*)d_in[9];
    float* out = (float*)d_out;

    // workspace carve-out
    char* ws = (char*)d_ws;
    size_t o = 0;
    auto alloc = [&](size_t bytes) -> void* {
        o = (o + 255) & ~(size_t)255;
        void* p = ws + o;
        o += bytes;
        return p;
    };
    int*    cnt    = (int*)alloc((size_t)N * 4);          // deg counts, later cursor
    int*    rowptr = (int*)alloc((size_t)(N + 1) * 4);
    float*  dinv   = (float*)alloc((size_t)N * 4);
    int*    bsum   = (int*)alloc(512 * 4);
    int2*   em     = (int2*)alloc((size_t)ETOT * 8);      // packed {col, nrm}
    float*  agg    = (float*)alloc((size_t)N * HIDDEN * 4);
    __half* x16    = (__half*)alloc((size_t)N * IN_DIM * 2);
    __half* h16    = (__half*)alloc((size_t)N * HIDDEN * 2);
    (void)ws_size;

    const int gN = (N + 255) / 256;          // 391
    const int gE = (E + 255) / 256;          // 6250
    const int gT = (ETOT + 255) / 256;       // 6641
    const int gAgg = (N + 3) / 4;            // 25000 (4 nodes/block)
    const int gGemm = (N + 127) / 128;       // 782
    const int gCast = (N * IN_DIM / 8 + 255) / 256;

    // CSR build + x cast (independent, same stream)
    init_cnt_k<<<gN, 256, 0, stream>>>(cnt, N);
    count_k<<<gE, 256, 0, stream>>>(dstA, cnt, E);
    scan_block_k<<<gN, 256, 0, stream>>>(cnt, rowptr, bsum, dinv, N);
    scan_bsum_k<<<1, 512, 0, stream>>>(bsum, gN);
    scan_add_k<<<gN, 256, 0, stream>>>(rowptr, bsum, cnt /*cursor*/, N, ETOT);
    fill_k<<<gT, 256, 0, stream>>>(srcA, dstA, dinv, cnt, em, E, N);
    cast16_k<<<gCast, 256, 0, stream>>>(x, x16, N * IN_DIM / 8);

    // layer 1: h16 = fp16(relu(Agg(x16) @ W1 + b1))   (aggregate in 64-dim)
    agg_k<64><<<gAgg, 256, 0, stream>>>(x16, rowptr, em, agg, N);
    gemm128_k<64, true, false, __half><<<gGemm, 256, 0, stream>>>(agg, W1, nullptr, b1, nullptr,
                                                                  h16, nullptr, N);

    // layer 2: h16 = fp16(relu(Agg(h16) @ W2 + b2))
    agg_k<128><<<gAgg, 256, 0, stream>>>(h16, rowptr, em, agg, N);
    gemm128_k<128, true, false, __half><<<gGemm, 256, 0, stream>>>(agg, W2, nullptr, b2, nullptr,
                                                                   h16, nullptr, N);

    // heads: aggregate once, ONE fused GEMM (cols 0..63 = mu, 64..127 = logvar), fp32 out
    agg_k<128><<<gAgg, 256, 0, stream>>>(h16, rowptr, em, agg, N);
    gemm128_k<128, false, true, float><<<gGemm, 256, 0, stream>>>(agg, Wmu, Wlv, bmu, blv,
                                                                  out, out + (size_t)N * Z_DIM, N);
}